// Round 12
// baseline (288.714 us; speedup 1.0000x reference)
//
#include <hip/hip_runtime.h>
#include <stdint.h>

// ModeloNeuralVasicek — two-phase mean-recursion.
// Round 28: Jacobi-anchor phase2. R27 (pipeline pairing) regressed 270->288:
// barrier-aligned waves contend instead of hiding stalls. Root cause of
// phase2's ~143us: the 41-body SEQUENTIAL chain. But bodies depend on r only
// through the batch ANCHOR (tangent corrects the rest), so use fixed-point
// iteration instead of sequential discovery:
//  pass1: anchors=r0 -> all 40 batches' coefficients computed IN PARALLEL
//         (no barrier in sweep; each wave computes its mlp's FULL h1 into a
//         private double-buffered LDS region -> no cross-wave h1 dependence),
//         per-batch 64-lane affine compose -> (B_k,A_k), one-wave scan of 40
//         composites -> r_entry[k].
//  pass2: anchors=r_entry (<=64 steps, closer than R26's 160-step drift
//         prediction); error contracts quadratically (~1e-6 final).
//  area from pass-2 per-lane partials x pass-2 entries.
// Phase1 byte-identical to R26 (121.5us, near VALU floor).

#define NSTEPS 2520
#define NB 64
#define NT 256
#define NQ 256
#define NMAT 7
#define NBODY 40
#define MWPAD 2560

typedef uint32_t u32x4 __attribute__((ext_vector_type(4)));
typedef float f32x4 __attribute__((ext_vector_type(4)));

// 1-op rotate: alignbit(v,v,32-n) = (v<<n)|(v>>(32-n))
__device__ __forceinline__ uint32_t rotl32(uint32_t v, int n) {
  return __builtin_amdgcn_alignbit(v, v, (uint32_t)(32 - n));
}

// Threefry-2x32, 20 rounds — matches jax._src.prng.threefry2x32 exactly.
__device__ __forceinline__ void tf2x32(uint32_t k0, uint32_t k1,
                                       uint32_t x0, uint32_t x1,
                                       uint32_t& o0, uint32_t& o1) {
  const uint32_t k2 = k0 ^ k1 ^ 0x1BD11BDAu;
  x0 += k0; x1 += k1;
#define R4(a,b,c,d) \
  x0 += x1; x1 = rotl32(x1,(a)); x1 ^= x0; \
  x0 += x1; x1 = rotl32(x1,(b)); x1 ^= x0; \
  x0 += x1; x1 = rotl32(x1,(c)); x1 ^= x0; \
  x0 += x1; x1 = rotl32(x1,(d)); x1 ^= x0;
  R4(13,15,26,6)  x0 += k1; x1 += k2 + 1u;
  R4(17,29,16,24) x0 += k2; x1 += k0 + 2u;
  R4(13,15,26,6)  x0 += k0; x1 += k1 + 3u;
  R4(17,29,16,24) x0 += k1; x1 += k2 + 4u;
  R4(13,15,26,6)  x0 += k2; x1 += k0 + 5u;
  o0 = x0; o1 = x1;
}

// fast reciprocal: v_rcp + one Newton step (~1e-7 rel)
__device__ __forceinline__ float fast_rcp(float q) {
  float r = __builtin_amdgcn_rcpf(q);
  r = __builtin_fmaf(r, __builtin_fmaf(-q, r, 1.0f), r);
  return r;
}

// Eigen/XLA generic_fast_tanh_float (context aggregator only).
__device__ __forceinline__ float eigen_tanh(float a_x) {
  float x = fminf(fmaxf(a_x, -7.90531110763549805f), 7.90531110763549805f);
  float x2 = x * x;
  float p = __builtin_fmaf(x2, -2.76076847742355e-16f, 2.00018790482477e-13f);
  p = __builtin_fmaf(x2, p, -8.60467152213735e-11f);
  p = __builtin_fmaf(x2, p, 5.12229709037114e-08f);
  p = __builtin_fmaf(x2, p, 1.48572235717979e-05f);
  p = __builtin_fmaf(x2, p, 6.37261928875436e-04f);
  p = __builtin_fmaf(x2, p, 4.89352455891786e-03f);
  p = x * p;
  float q = __builtin_fmaf(x2, 1.19825839466702e-06f, 1.18534705686654e-04f);
  q = __builtin_fmaf(x2, q, 2.26843463243900e-03f);
  q = __builtin_fmaf(x2, q, 4.89352518554385e-03f);
  float rr = p / q;
  return (fabsf(a_x) < 0.0004f) ? a_x : rr;
}

// Eigen/XLA erf polynomial with rcp-division.
__device__ __forceinline__ float eigen_erf_fast(float a_x) {
  float x = fminf(fmaxf(a_x, -4.0f), 4.0f);
  float x2 = x * x;
  float p = __builtin_fmaf(x2, -2.72614225801306e-10f, 2.77068142495902e-08f);
  p = __builtin_fmaf(x2, p, -2.10102402082508e-06f);
  p = __builtin_fmaf(x2, p, -5.69250639462346e-05f);
  p = __builtin_fmaf(x2, p, -7.34990630326855e-04f);
  p = __builtin_fmaf(x2, p, -2.95459980854025e-03f);
  p = __builtin_fmaf(x2, p, -1.60960333262415e-02f);
  p = x * p;
  float q = __builtin_fmaf(x2, -1.45660718464996e-05f, -2.13374055278905e-04f);
  q = __builtin_fmaf(x2, q, -1.68282697438203e-03f);
  q = __builtin_fmaf(x2, q, -7.37332916720468e-03f);
  q = __builtin_fmaf(x2, q, -1.42647390514189e-02f);
  return p * fast_rcp(q);
}

__device__ __forceinline__ uint16_t f32_to_f16bits(float x) {
  _Float16 hv = (_Float16)x;  // RNE
  return __builtin_bit_cast(uint16_t, hv);
}

__device__ __forceinline__ uint32_t pack_f16x2(float lo, float hi) {
  return (uint32_t)f32_to_f16bits(lo) | ((uint32_t)f32_to_f16bits(hi) << 16);
}

// DPP add: v += dpp_move(v). 0x111..0x118 row_shr; 0x142/0x143 row_bcast.
template <int CTRL, int RMASK>
__device__ __forceinline__ float dpp_add(float v) {
  int x = __builtin_amdgcn_update_dpp(0, __float_as_int(v), CTRL, RMASK, 0xf, true);
  return v + __int_as_float(x);
}

// full-wave sum -> lane 63 (validated chain)
__device__ __forceinline__ float dpp_reduce63(float p) {
  p = dpp_add<0x111, 0xf>(p);
  p = dpp_add<0x112, 0xf>(p);
  p = dpp_add<0x114, 0xf>(p);
  p = dpp_add<0x118, 0xf>(p);
  p = dpp_add<0x142, 0xa>(p);
  p = dpp_add<0x143, 0xc>(p);
  return p;
}

// DPP move with explicit identity; RMASK gates receiving rows (others keep
// OLD); bound_ctrl=false keeps OLD for no-src lanes.
template <int CTRL, int RMASK>
__device__ __forceinline__ float dpp_mov(float v, float old) {
  int x = __builtin_amdgcn_update_dpp(__float_as_int(old), __float_as_int(v),
                                      CTRL, RMASK, 0xf, false);
  return __int_as_float(x);
}

// inclusive 64-lane affine scan (validated in R25/R26): (B,A) per lane.
__device__ __forceinline__ void affine_scan64(float& B, float& A) {
  float Bs, As;
  Bs = dpp_mov<0x111, 0xf>(B, 1.0f); As = dpp_mov<0x111, 0xf>(A, 0.0f);
  A = __builtin_fmaf(B, As, A); B = B * Bs;
  Bs = dpp_mov<0x112, 0xf>(B, 1.0f); As = dpp_mov<0x112, 0xf>(A, 0.0f);
  A = __builtin_fmaf(B, As, A); B = B * Bs;
  Bs = dpp_mov<0x114, 0xf>(B, 1.0f); As = dpp_mov<0x114, 0xf>(A, 0.0f);
  A = __builtin_fmaf(B, As, A); B = B * Bs;
  Bs = dpp_mov<0x118, 0xf>(B, 1.0f); As = dpp_mov<0x118, 0xf>(A, 0.0f);
  A = __builtin_fmaf(B, As, A); B = B * Bs;
  Bs = dpp_mov<0x142, 0xa>(B, 1.0f); As = dpp_mov<0x142, 0xa>(A, 0.0f);
  A = __builtin_fmaf(B, As, A); B = B * Bs;
  Bs = dpp_mov<0x143, 0xc>(B, 1.0f); As = dpp_mov<0x143, 0xc>(A, 0.0f);
  A = __builtin_fmaf(B, As, A); B = B * Bs;
}

__device__ __forceinline__ float readlane_f(float v, int l) {
  return __int_as_float(__builtin_amdgcn_readlane(__float_as_int(v), l));
}

#define DTF  0.00396825396825396826f
#define SQDT 0.06299407883487120442f
#define TSTEP (1.0f / 2519.0f)
#define TSC      64.0f
#define TSC_INV  0.015625f
#define TSC_T    1024.0f
#define TSCT_INV 0.0009765625f
#define INV_SQRT2 0.7071067811865475f
#define PHI_C     0.3989422804014327f
#define NEG_LN2  -0.69314718055994530942f
#define LG2_W5   -7.2134752044448170368f
#define NRM_C    0.08908708063747479f

// ---------------- Phase 1: mean_dW[b][s] — fully parallel ----------------
__global__ __launch_bounds__(256)
void vasicek_phase1_meandw(float* __restrict__ ws) {
  const int tid = threadIdx.x;
  const int lane = tid & 63;
  const int wv = tid >> 6;
  const int wid = blockIdx.x * 4 + wv;          // 0 .. 64*2520-1
  const int b = wid / NSTEPS;
  const int s = wid - b * NSTEPS;

  uint32_t kA, kB;
  tf2x32(0u, 1u, 0u, (uint32_t)s, kA, kB);      // split(key(1))[s]
  const uint32_t k2 = kA ^ kB ^ 0x1BD11BDAu;
  const uint32_t x1base = (uint32_t)(b * NQ + lane) + kB;  // pre-keyed x1

  const float MINVAL = -0.999999940395355224609375f;
  float sum = 0.f;
#pragma unroll
  for (int i = 0; i < 4; ++i) {
    uint32_t x0 = kA, x1 = x1base + (uint32_t)(i * 64);
    R4(13,15,26,6)  x0 += kB; x1 += k2 + 1u;
    R4(17,29,16,24) x0 += k2; x1 += kA + 2u;
    R4(13,15,26,6)  x0 += kA; x1 += kB + 3u;
    R4(17,29,16,24) x0 += kB; x1 += k2 + 4u;
    R4(13,15,26,6)  x0 += k2; x1 += kA + 5u;
    const uint32_t bits = x0 ^ x1;

    uint32_t fb = (bits >> 9) | 0x3F800000u;
    float u = __builtin_fmaf(__uint_as_float(fb) - 1.0f, 2.0f, MINVAL);
    u = fmaxf(u, MINVAL);
    float omsq = __builtin_fmaf(u, -u, 1.0f);
    float lg = __builtin_amdgcn_logf(omsq);
    float wc = __builtin_fmaf(lg, NEG_LN2, -2.5f);
    float p = 2.81022636e-08f;
    p = __builtin_fmaf(p, wc, 3.43273939e-07f);
    p = __builtin_fmaf(p, wc, -3.5233877e-06f);
    p = __builtin_fmaf(p, wc, -4.39150654e-06f);
    p = __builtin_fmaf(p, wc, 0.00021858087f);
    p = __builtin_fmaf(p, wc, -0.00125372503f);
    p = __builtin_fmaf(p, wc, -0.00417768164f);
    p = __builtin_fmaf(p, wc, 0.246640727f);
    p = __builtin_fmaf(p, wc, 1.50140941f);
    if (__ballot(lg <= LG2_W5)) {                      // rare (~0.3% lanes)
      float w = lg * NEG_LN2;
      float wsr = sqrtf(w) - 3.0f;
      float pr = -0.000200214257f;
      pr = __builtin_fmaf(pr, wsr, 0.000100950558f);
      pr = __builtin_fmaf(pr, wsr, 0.00134934322f);
      pr = __builtin_fmaf(pr, wsr, -0.00367342844f);
      pr = __builtin_fmaf(pr, wsr, 0.00573950773f);
      pr = __builtin_fmaf(pr, wsr, -0.0076224613f);
      pr = __builtin_fmaf(pr, wsr, 0.00943887047f);
      pr = __builtin_fmaf(pr, wsr, 1.00167406f);
      pr = __builtin_fmaf(pr, wsr, 2.83297682f);
      p = (lg <= LG2_W5) ? pr : p;
    }
    sum = __builtin_fmaf(p * u, NRM_C, sum);
  }
  sum += __shfl_xor(sum, 32, 64); sum += __shfl_xor(sum, 16, 64);
  sum += __shfl_xor(sum, 8, 64);  sum += __shfl_xor(sum, 4, 64);
  sum += __shfl_xor(sum, 2, 64);  sum += __shfl_xor(sum, 1, 64);
  if (lane == 0) ws[b * NSTEPS + s] = sum * (1.0f / 256.0f);
}

// ---- B-fragment machinery, k-PERMUTED (unchanged from R20/R23):
// B dword d of K-chunk T (lane q,n) holds W2 rows (16T+4q+d, 64+16T+4q+d)
// at column 16*(4*half+C) + n, f16x2 packed.
#define BDECL(T, C) u32x4 b_##T##_##C;
#define BINIT(T, C) { \
  const int col_ = 16 * (4 * half + (C)) + n; \
  const int r0_ = 16 * (T) + 4 * q; \
  b_##T##_##C = (u32x4){ \
    pack_f16x2(W2src[(r0_ + 0) * 128 + col_], W2src[(r0_ + 64) * 128 + col_]), \
    pack_f16x2(W2src[(r0_ + 1) * 128 + col_], W2src[(r0_ + 65) * 128 + col_]), \
    pack_f16x2(W2src[(r0_ + 2) * 128 + col_], W2src[(r0_ + 66) * 128 + col_]), \
    pack_f16x2(W2src[(r0_ + 3) * 128 + col_], W2src[(r0_ + 67) * 128 + col_])}; \
  asm volatile("" : "+a"(b_##T##_##C)); /* pin in AGPR quad */ \
}
#define MFMA1(ACC, AF, BF) \
  asm("v_mfma_f32_16x16x32_f16 %0, %1, %2, %0" : "+v"(ACC) : "v"(AF), "a"(BF));

// ---------------- Phase 2: Jacobi-anchor scan, 64 blocks x 256 -------------
__global__
__attribute__((amdgpu_flat_work_group_size(256, 256)))
void vasicek_phase2_scan(
    const float* __restrict__ X, const float* __restrict__ r_ult,
    const float* __restrict__ mats,
    const float* __restrict__ Wp, const float* __restrict__ bp,
    const float* __restrict__ ln_g, const float* __restrict__ ln_b,
    const float* __restrict__ muW1, const float* __restrict__ mub1,
    const float* __restrict__ muW2, const float* __restrict__ mub2,
    const float* __restrict__ muW3, const float* __restrict__ mub3,
    const float* __restrict__ siW1, const float* __restrict__ sib1,
    const float* __restrict__ siW2, const float* __restrict__ sib2,
    const float* __restrict__ siW3, const float* __restrict__ sib3,
    const float* __restrict__ ws, float* __restrict__ out) {
  // per-wave PRIVATE double-buffered h1: [buf][wave][region][68 dw]
  __shared__ __align__(16) uint32_t h1p[2][4][4][68];
  __shared__ __align__(16) float meanw[MWPAD];
  __shared__ float part[256];                 // ctx scratch + scan scratch
  __shared__ float mbuf[64];
  __shared__ float ctx_lds[192];
  __shared__ float c1buf[2][128];
  __shared__ __align__(16) float msum_l[NBODY][4][4];   // [k][wave][PV,PR,PT,pad]
  __shared__ __align__(8)  float part_lds[NBODY][64][2];// per-lane (B,A) partials
  __shared__ __align__(8)  float bsc[NBODY][2];         // batch composites
  __shared__ float re_lds[NBODY];                       // batch-entry states
  __shared__ float areas[4];

  const int t = threadIdx.x;
  const int b = blockIdx.x;
  const int lane = t & 63;
  const int wv = t >> 6;

  for (int i = t; i < MWPAD; i += 256)
    meanw[i] = i < NSTEPS ? ws[b * NSTEPS + i] : 0.f;

  // ---- context aggregator (all 256 threads, one T-row each) ----
  float h[64];
  {
    float x0 = X[(b * NT + t) * 2 + 0];
    float x1 = X[(b * NT + t) * 2 + 1];
    float s = 0.f;
#pragma unroll
    for (int c = 0; c < 64; ++c) {
      float pre = __builtin_fmaf(x1, Wp[64 + c], x0 * Wp[c]) + bp[c];
      h[c] = eigen_tanh(pre);
      s += h[c];
    }
    float m = s * 0.015625f;
    float vs = 0.f;
#pragma unroll
    for (int c = 0; c < 64; ++c) { float d = h[c] - m; vs = __builtin_fmaf(d, d, vs); }
    float den = sqrtf(vs * 0.015625f + 1e-5f);
#pragma unroll
    for (int c = 0; c < 64; ++c)
      h[c] = ((h[c] - m) / den) * ln_g[c] + ln_b[c];
  }
#pragma unroll
  for (int c = 0; c < 64; ++c) {
    float v = h[c];
    v += __shfl_xor(v, 32, 64); v += __shfl_xor(v, 16, 64);
    v += __shfl_xor(v, 8, 64);  v += __shfl_xor(v, 4, 64);
    v += __shfl_xor(v, 2, 64);  v += __shfl_xor(v, 1, 64);
    if (lane == 0) part[wv * 64 + c] = v;
  }
  __syncthreads();
  if (t < 64) {
    float m = ((part[t] + part[64 + t]) + (part[128 + t] + part[192 + t])) * (1.0f / 256.0f);
    mbuf[t] = m;
    ctx_lds[t] = m;
  }
  __syncthreads();
#pragma unroll
  for (int c = 0; c < 64; ++c) {
    float d = h[c] - mbuf[c];
    float v = d * d;
    v += __shfl_xor(v, 32, 64); v += __shfl_xor(v, 16, 64);
    v += __shfl_xor(v, 8, 64);  v += __shfl_xor(v, 4, 64);
    v += __shfl_xor(v, 2, 64);  v += __shfl_xor(v, 1, 64);
    if (lane == 0) part[wv * 64 + c] = v;
  }
  if (t == 255) {
#pragma unroll
    for (int c = 0; c < 64; ++c) ctx_lds[128 + c] = h[c];
  }
  __syncthreads();
  if (t < 64) {
    float vs = (part[t] + part[64 + t]) + (part[128 + t] + part[192 + t]);
    ctx_lds[64 + t] = sqrtf(vs / 255.0f);
  }
  __syncthreads();

  // ---- c1 columns: wave (mlp=wv>>1, half=wv&1) computes its 64 -> c1buf ----
  const int mlp = wv >> 1;
  const int half = wv & 1;
  {
    const int jH = 64 * half + lane;
    const float* W1c = mlp == 0 ? muW1 : siW1;
    float c1 = (mlp == 0 ? mub1 : sib1)[jH];
    for (int c = 0; c < 192; ++c) {
      const float cx = ctx_lds[c];
      c1 = __builtin_fmaf(cx, W1c[(2 + c) * 128 + jH], c1);
    }
    c1buf[mlp][jH] = c1;
  }
  // zero region 3 of both private h1 buffers for this wave
  h1p[0][wv][3][lane] = 0u; h1p[1][wv][3][lane] = 0u;
  if (lane < 4) { h1p[0][wv][3][64 + lane] = 0u; h1p[1][wv][3][64 + lane] = 0u; }
  __syncthreads();

  // ---- per-wave constants: FULL h1 of this wave's mlp (both 64-halves) ----
  const float* W1 = mlp == 0 ? muW1 : siW1;
  const float* W2src = mlp == 0 ? muW2 : siW2;
  const float c1a = c1buf[mlp][lane];
  const float c1b = c1buf[mlp][64 + lane];
  const float w10a = W1[lane],        w11a = W1[128 + lane];
  const float w10b = W1[64 + lane],   w11b = W1[192 + lane];
  const float w10aS = w10a * TSC,     w10bS = w10b * TSC;
  const float w11aT = w11a * (TSTEP * TSC_T), w11bT = w11b * (TSTEP * TSC_T);
  const float b3mu = mub3[0], b3si = sib3[0];

  const int q = lane >> 4, n = lane & 15;
  const float* b2p = mlp == 0 ? mub2 : sib2;
  const float* w3p = mlp == 0 ? muW3 : siW3;
  const int colE = 64 * half + 16 * q + n;
  const float b2E = b2p[colE], w3E = w3p[colE];

  BDECL(0,0) BDECL(0,1) BDECL(0,2) BDECL(0,3)
  BDECL(1,0) BDECL(1,1) BDECL(1,2) BDECL(1,3)
  BDECL(2,0) BDECL(2,1) BDECL(2,2) BDECL(2,3)
  BDECL(3,0) BDECL(3,1) BDECL(3,2) BDECL(3,3)
  BINIT(0,0) BINIT(0,1) BINIT(0,2) BINIT(0,3)
  BINIT(1,0) BINIT(1,1) BINIT(1,2) BINIT(1,3)
  BINIT(2,0) BINIT(2,1) BINIT(2,2) BINIT(2,3)
  BINIT(3,0) BINIT(3,1) BINIT(3,2) BINIT(3,3)

  const float r0 = r_ult[b];
  const float jj = (float)lane - 31.5f;

  // ---- two Jacobi passes: sweep (parallel) -> combine -> global scan ----
#pragma unroll 1
  for (int pass = 0; pass < 2; ++pass) {
    // --- sweep: 40 independent batches per wave (no barrier inside) ---
#pragma unroll 2
    for (int k = 0; k < NBODY; ++k) {
      const float aK = pass == 0 ? r0 : re_lds[k];
      const float tvk = TSTEP * ((float)(64 * k) + 31.5f);
      const int hb = k & 1;
      // layer-1: full h1 of this wave's mlp (both halves), val/dr/dt regions
      float prea = __builtin_fmaf(tvk, w11a, __builtin_fmaf(aK, w10a, c1a));
      float preb = __builtin_fmaf(tvk, w11b, __builtin_fmaf(aK, w10b, c1b));
      float ea = eigen_erf_fast(prea * INV_SQRT2);
      float ca = (ea + 1.0f) * 0.5f;
      float va = prea * ca;
      float pha = PHI_C * __expf(-0.5f * prea * prea);
      float gpa = __builtin_fmaf(prea, pha, ca);
      float eb = eigen_erf_fast(preb * INV_SQRT2);
      float cb = (eb + 1.0f) * 0.5f;
      float vb = preb * cb;
      float phb = PHI_C * __expf(-0.5f * preb * preb);
      float gpb = __builtin_fmaf(preb, phb, cb);
      h1p[hb][wv][0][lane] = pack_f16x2(va, vb);
      h1p[hb][wv][1][lane] = pack_f16x2(gpa * w10aS, gpb * w10bS);
      h1p[hb][wv][2][lane] = pack_f16x2(gpa * w11aT, gpb * w11bT);
      // A-frags (same-wave write->read; in-order at LDS unit)
      const u32x4* hq = ((const u32x4*)&h1p[hb][wv][0][0]) + 17 * (n & 3) + q;
      u32x4 af0 = hq[0], af1 = hq[4], af2 = hq[8], af3 = hq[12];
      f32x4 ac0 = {0,0,0,0}, ac1 = {0,0,0,0}, ac2 = {0,0,0,0}, ac3 = {0,0,0,0};
      MFMA1(ac0, af0, b_0_0) MFMA1(ac1, af0, b_0_1) MFMA1(ac2, af0, b_0_2) MFMA1(ac3, af0, b_0_3)
      MFMA1(ac0, af1, b_1_0) MFMA1(ac1, af1, b_1_1) MFMA1(ac2, af1, b_1_2) MFMA1(ac3, af1, b_1_3)
      MFMA1(ac0, af2, b_2_0) MFMA1(ac1, af2, b_2_1) MFMA1(ac2, af2, b_2_2) MFMA1(ac3, af2, b_2_3)
      MFMA1(ac0, af3, b_3_0) MFMA1(ac1, af3, b_3_1) MFMA1(ac2, af3, b_3_2) MFMA1(ac3, af3, b_3_3)
      asm volatile("s_nop 7\n\ts_nop 7"
                   : "+v"(ac0), "+v"(ac1), "+v"(ac2), "+v"(ac3));
      // epilogue: this lane's single column (chunk C=q)
      const f32x4 aq = q == 0 ? ac0 : q == 1 ? ac1 : q == 2 ? ac2 : ac3;
      float yv = aq[0] + b2E;
      float ev = eigen_erf_fast(yv * INV_SQRT2);
      float cv = (ev + 1.0f) * 0.5f;
      float pv = yv * cv * w3E;
      float phv = PHI_C * __expf(-0.5f * yv * yv);
      float g2p = __builtin_fmaf(yv, phv, cv) * w3E;
      float pr = g2p * aq[1];
      float pt = g2p * aq[2];
      pv = dpp_reduce63(pv);
      pr = dpp_reduce63(pr);
      pt = dpp_reduce63(pt);
      if (lane == 63) *(f32x4*)&msum_l[k][wv][0] = (f32x4){pv, pr, pt, 0.f};
    }
    __syncthreads();

    // --- combine: wave wv owns batches 10wv..10wv+9; lane = step-in-batch ---
    for (int kk = 0; kk < 10; ++kk) {
      const int k = 10 * wv + kk;
      f32x4 m0 = *(const f32x4*)&msum_l[k][0][0];
      f32x4 m1 = *(const f32x4*)&msum_l[k][1][0];
      f32x4 m2 = *(const f32x4*)&msum_l[k][2][0];
      f32x4 m3 = *(const f32x4*)&msum_l[k][3][0];
      const float aK = pass == 0 ? r0 : re_lds[k];
      const float mwj = meanw[64 * k + lane];
      float MV = (m0[0] + m1[0]) + b3mu;
      float MR = (m0[1] + m1[1]) * TSC_INV;
      float MT = (m0[2] + m1[2]) * TSCT_INV;
      float ZV = (m2[0] + m3[0]) + b3si;
      float ZR = (m2[1] + m3[1]) * TSC_INV;
      float ZT = (m2[2] + m3[2]) * TSCT_INV;
      float e_ = __expf(-fabsf(ZV));
      float sp = fmaxf(ZV, 0.f) + __logf(1.0f + e_) + 1e-5f;
      float inv = fast_rcp(1.0f + e_);
      float sgm = ZV > 0.f ? inv : 1.0f - inv;
      float hcv = 0.5f * sgm * (1.0f - sgm);
      float dzt = jj * ZT;
      float sigj = __builtin_fmaf(2.0f * hcv, dzt, sgm);
      float spj  = __builtin_fmaf(__builtin_fmaf(hcv, dzt, sgm), dzt, sp);
      float sZR = sigj * ZR;
      float beta = __builtin_fmaf(sZR, mwj, __builtin_fmaf(MR, DTF, 1.0f));
      float am_ = __builtin_fmaf(jj, MT, __builtin_fmaf(-aK, MR, MV));
      float as_ = __builtin_fmaf(-aK, sZR, spj);
      float alpha = __builtin_fmaf(am_, DTF, as_ * mwj);
      float B = beta, A = alpha;
      affine_scan64(B, A);
      part_lds[k][lane][0] = B;
      part_lds[k][lane][1] = A;
      if (lane == 63) { bsc[k][0] = B; bsc[k][1] = A; }
    }
    __syncthreads();

    // --- global scan over the 40 batch composites (wave 0 only) ---
    if (wv == 0) {
      float B = 1.0f, A = 0.0f;
      if (lane < NBODY) { B = bsc[lane][0]; A = bsc[lane][1]; }
      affine_scan64(B, A);
      float st = __builtin_fmaf(B, r0, A);   // state after batch `lane`
      part[lane] = st;                       // scratch (same-wave rd below)
      float re = lane == 0 ? r0 : part[lane - 1];  // same-wave LDS, in-order
      if (lane < NBODY) re_lds[lane] = re;
    }
    __syncthreads();
  }

  // ---- area: pass-2 partials x pass-2 entry states ----
  {
    float ap = 0.f;
    for (int kk = 0; kk < 10; ++kk) {
      const int k = 10 * wv + kk;
      float B = part_lds[k][lane][0];
      float A = part_lds[k][lane][1];
      float rho = __builtin_fmaf(B, re_lds[k], A);
      if (64 * k + lane < NSTEPS) ap = __builtin_fmaf(rho, DTF, ap);
    }
    ap = dpp_reduce63(ap);
    if (lane == 63) areas[wv] = ap;
  }
  __syncthreads();

  if (t < NMAT) {
    float area = (areas[0] + areas[1]) + (areas[2] + areas[3]);
    float mx = mats[0];
#pragma unroll
    for (int i = 1; i < NMAT; ++i) mx = fmaxf(mx, mats[i]);
    const float mm = mats[t];
    const float frac = mm / (mx + 1e-12f);
    out[b * NMAT + t] = (area * frac) / (mm + 1e-12f);
  }
}

extern "C" void kernel_launch(void* const* d_in, const int* in_sizes, int n_in,
                              void* d_out, int out_size, void* d_ws, size_t ws_size,
                              hipStream_t stream) {
  (void)in_sizes; (void)n_in; (void)ws_size; (void)out_size;
  const float* X      = (const float*)d_in[0];
  const float* r_ult  = (const float*)d_in[1];
  const float* mats   = (const float*)d_in[2];
  const float* Wp     = (const float*)d_in[3];
  const float* bp     = (const float*)d_in[4];
  const float* ln_g   = (const float*)d_in[5];
  const float* ln_b   = (const float*)d_in[6];
  const float* muW1   = (const float*)d_in[7];
  const float* mub1   = (const float*)d_in[8];
  const float* muW2   = (const float*)d_in[9];
  const float* mub2   = (const float*)d_in[10];
  const float* muW3   = (const float*)d_in[11];
  const float* mub3   = (const float*)d_in[12];
  const float* siW1   = (const float*)d_in[13];
  const float* sib1   = (const float*)d_in[14];
  const float* siW2   = (const float*)d_in[15];
  const float* sib2   = (const float*)d_in[16];
  const float* siW3   = (const float*)d_in[17];
  const float* sib3   = (const float*)d_in[18];
  float* ws = (float*)d_ws;   // 64*2520*4 = 645,120 bytes

  hipLaunchKernelGGL(vasicek_phase1_meandw,
                     dim3(NB * NSTEPS / 4), dim3(256), 0, stream, ws);
  hipLaunchKernelGGL(vasicek_phase2_scan,
                     dim3(NB), dim3(256), 0, stream,
                     X, r_ult, mats, Wp, bp, ln_g, ln_b,
                     muW1, mub1, muW2, mub2, muW3, mub3,
                     siW1, sib1, siW2, sib2, siW3, sib3,
                     ws, (float*)d_out);
}